// Round 1
// baseline (2245.306 us; speedup 1.0000x reference)
//
#include <hip/hip_runtime.h>
#include <cstdint>

#define KNN 20
#define BV 8
#define NV 1024

// ---------- transpose x [B,N,3] -> hx [B,3,N]
__global__ __launch_bounds__(256) void k_transpose(const float* __restrict__ x, float* __restrict__ hx) {
    int id = blockIdx.x * 256 + threadIdx.x;
    if (id >= BV * 3 * NV) return;
    int n = id % NV;
    int c = (id / NV) % 3;
    int b = id / (3 * NV);
    hx[id] = x[(b * NV + n) * 3 + c];
}

// ---------- xx[b][n] = sum_c h[b][c][n]^2  (sequential over c, matches k_dist order)
__global__ __launch_bounds__(256) void k_xx(const float* __restrict__ h, float* __restrict__ xx,
                                            int C, int bstride) {
    int id = blockIdx.x * 256 + threadIdx.x;
    int n = id % NV, b = id / NV;
    if (b >= BV) return;
    const float* hp = h + (size_t)b * bstride + n;
    float s = 0.f;
    for (int c = 0; c < C; ++c) { float v = hp[(size_t)c * NV]; s += v * v; }
    xx[b * NV + n] = s;
}

// ---------- D[b][i][j] = 2*sum_c h[c,i]h[c,j] - xx[i] - xx[j]   (neg sq dist)
__global__ __launch_bounds__(256) void k_dist(const float* __restrict__ h, const float* __restrict__ xx,
                                              float* __restrict__ D, int C, int bstride) {
    __shared__ float As[8][65], Bs[8][65];
    const int b = blockIdx.z, i0 = blockIdx.y * 64, j0 = blockIdx.x * 64;
    const int t = threadIdx.x, tx = t & 15, ty = t >> 4;
    float acc[4][4] = {};
    const float* hb = h + (size_t)b * bstride;
    for (int c0 = 0; c0 < C; c0 += 8) {
#pragma unroll
        for (int e = 0; e < 2; ++e) {
            int ee = t + e * 256;
            int cc = ee >> 6, ii = ee & 63;
            bool ok = (c0 + cc) < C;
            As[cc][ii] = ok ? hb[(size_t)(c0 + cc) * NV + i0 + ii] : 0.f;
            Bs[cc][ii] = ok ? hb[(size_t)(c0 + cc) * NV + j0 + ii] : 0.f;
        }
        __syncthreads();
#pragma unroll
        for (int c = 0; c < 8; ++c) {
            float ar[4], br[4];
#pragma unroll
            for (int a = 0; a < 4; ++a) { ar[a] = As[c][ty * 4 + a]; br[a] = Bs[c][tx * 4 + a]; }
#pragma unroll
            for (int a = 0; a < 4; ++a)
#pragma unroll
                for (int q = 0; q < 4; ++q) acc[a][q] += ar[a] * br[q];
        }
        __syncthreads();
    }
    const float* xb = xx + b * NV;
#pragma unroll
    for (int a = 0; a < 4; ++a) {
        int i = i0 + ty * 4 + a;
        float xi = xb[i];
#pragma unroll
        for (int q = 0; q < 4; ++q) {
            int j = j0 + tx * 4 + q;
            D[(size_t)b * NV * NV + (size_t)i * NV + j] = 2.f * acc[a][q] - xi - xb[j];
        }
    }
}

// ---------- top-20 per row (largest values = nearest). 64 threads = 64 rows/block.
__global__ __launch_bounds__(64) void k_topk(const float* __restrict__ D, int* __restrict__ idx) {
    __shared__ float Ls[64][129];
    const int b = blockIdx.y, r0 = blockIdx.x * 64, t = threadIdx.x;
    float tv[KNN]; int ti[KNN];
#pragma unroll
    for (int s = 0; s < KNN; ++s) { tv[s] = -3.4e38f; ti[s] = 0; }
    const float* Db = D + (size_t)b * NV * NV + (size_t)r0 * NV;
    for (int c0 = 0; c0 < NV; c0 += 128) {
        for (int e = 0; e < 128; ++e) {
            int ee = e * 64 + t;
            int rr = ee >> 7, jj = ee & 127;
            Ls[rr][jj] = Db[(size_t)rr * NV + c0 + jj];
        }
        __syncthreads();
        for (int j = 0; j < 128; ++j) {
            float v = Ls[t][j];
            if (v > tv[KNN - 1]) {  // strict >: ties keep lower index (scan order)
                tv[KNN - 1] = v; ti[KNN - 1] = c0 + j;
#pragma unroll
                for (int s = KNN - 1; s > 0; --s) {
                    if (tv[s] > tv[s - 1]) {
                        float fv = tv[s]; tv[s] = tv[s - 1]; tv[s - 1] = fv;
                        int iv = ti[s]; ti[s] = ti[s - 1]; ti[s - 1] = iv;
                    }
                }
            }
        }
        __syncthreads();
    }
    int* op = idx + ((size_t)b * NV + r0 + t) * KNN;
#pragma unroll
    for (int s = 0; s < KNN; ++s) op[s] = ti[s];
}

// ---------- Wd[o][c] = W[o][C+c] - W[o][c]
__global__ __launch_bounds__(256) void k_wd(const float* __restrict__ W, float* __restrict__ Wd, int C, int O) {
    int id = blockIdx.x * 256 + threadIdx.x;
    if (id >= O * C) return;
    int c = id % C, o = id / C;
    Wd[id] = W[(size_t)o * 2 * C + C + c] - W[(size_t)o * 2 * C + c];
}

// ---------- out[b][o][n] = sum_c A[o][c] * h[b][c][n]
__global__ __launch_bounds__(256) void k_gemm(const float* __restrict__ A, int astride,
                                              const float* __restrict__ h, int bstride, int C,
                                              float* __restrict__ out, int O) {
    __shared__ float Ws[8][65], Hs[8][65];
    const int b = blockIdx.z, o0 = blockIdx.y * 64, n0 = blockIdx.x * 64;
    const int t = threadIdx.x, tx = t & 15, ty = t >> 4;
    float acc[4][4] = {};
    const float* hb = h + (size_t)b * bstride;
    for (int c0 = 0; c0 < C; c0 += 8) {
#pragma unroll
        for (int e = 0; e < 2; ++e) {
            int ee = t + e * 256;
            {   // W tile: cc-fast within a row
                int cc = ee & 7, oo = ee >> 3;
                Ws[cc][oo] = ((c0 + cc) < C) ? A[(size_t)(o0 + oo) * astride + c0 + cc] : 0.f;
            }
            {   // H tile: nn-fast (coalesced)
                int cc = ee >> 6, nn = ee & 63;
                Hs[cc][nn] = ((c0 + cc) < C) ? hb[(size_t)(c0 + cc) * NV + n0 + nn] : 0.f;
            }
        }
        __syncthreads();
#pragma unroll
        for (int c = 0; c < 8; ++c) {
            float ar[4], br[4];
#pragma unroll
            for (int a = 0; a < 4; ++a) { ar[a] = Ws[c][ty * 4 + a]; br[a] = Hs[c][tx * 4 + a]; }
#pragma unroll
            for (int a = 0; a < 4; ++a)
#pragma unroll
                for (int q = 0; q < 4; ++q) acc[a][q] += ar[a] * br[q];
        }
        __syncthreads();
    }
#pragma unroll
    for (int a = 0; a < 4; ++a) {
        int o = o0 + ty * 4 + a;
#pragma unroll
        for (int q = 0; q < 4; ++q) {
            int n = n0 + tx * 4 + q;
            out[((size_t)b * O + o) * NV + n] = acc[a][q];
        }
    }
}

// ---------- h_out[b][o][n] = mean_k lrelu( a*(p[b][o][idx[n][k]] + d[b][o][n]) + c0 )
__global__ __launch_bounds__(256) void k_edge(const float* __restrict__ p, const float* __restrict__ dd,
                                              const int* __restrict__ idx,
                                              const float* __restrict__ ga, const float* __restrict__ be,
                                              const float* __restrict__ mu, const float* __restrict__ va,
                                              float* __restrict__ out, int out_bstride, int O) {
    const int n = blockIdx.x * 256 + threadIdx.x;
    const int o = blockIdx.y, b = blockIdx.z;
    const float a  = ga[o] / sqrtf(va[o] + 1e-5f);
    const float c0 = be[o] - mu[o] * a;
    const float* pb = p + ((size_t)b * O + o) * NV;
    const float dv  = dd[((size_t)b * O + o) * NV + n];
    const int* ip   = idx + ((size_t)b * NV + n) * KNN;
    float s = 0.f;
#pragma unroll
    for (int k = 0; k < KNN; ++k) {
        int j = ip[k];
        float y = fmaf(a, pb[j] + dv, c0);
        s += (y > 0.f) ? y : 0.2f * y;
    }
    out[(size_t)b * out_bstride + (size_t)o * NV + n] = s * (1.f / KNN);
}

// ---------- pooled[b][o] = mean_n hf[b][o][n]
__global__ __launch_bounds__(256) void k_pool(const float* __restrict__ hf, float* __restrict__ pooled) {
    const int o = blockIdx.x, b = blockIdx.y;
    const float* hp = hf + ((size_t)b * 512 + o) * NV;
    float s = 0.f;
    for (int i = threadIdx.x; i < NV; i += 256) s += hp[i];
#pragma unroll
    for (int off = 32; off > 0; off >>= 1) s += __shfl_down(s, off, 64);
    __shared__ float red[4];
    if ((threadIdx.x & 63) == 0) red[threadIdx.x >> 6] = s;
    __syncthreads();
    if (threadIdx.x == 0)
        pooled[(size_t)b * 512 + o] = (red[0] + red[1] + red[2] + red[3]) * (1.f / NV);
}

// ---------- out[b][j] = sum_o pooled[b][o] * We[j][o]
__global__ __launch_bounds__(256) void k_final(const float* __restrict__ pooled, const float* __restrict__ We,
                                               float* __restrict__ out) {
    const int j = threadIdx.x, b = blockIdx.x;
    __shared__ float ps[512];
    for (int o = threadIdx.x; o < 512; o += 256) ps[o] = pooled[b * 512 + o];
    __syncthreads();
    float s = 0.f;
    for (int o = 0; o < 512; ++o) s += ps[o] * We[(size_t)j * 512 + o];
    out[b * 256 + j] = s;
}

extern "C" void kernel_launch(void* const* d_in, const int* in_sizes, int n_in,
                              void* d_out, int out_size, void* d_ws, size_t ws_size,
                              hipStream_t stream) {
    const float* x  = (const float*)d_in[0];
    const float* W0 = (const float*)d_in[1];
    const float* g0 = (const float*)d_in[2];
    const float* b0 = (const float*)d_in[3];
    const float* m0 = (const float*)d_in[4];
    const float* v0 = (const float*)d_in[5];
    const float* W1 = (const float*)d_in[6];
    const float* g1 = (const float*)d_in[7];
    const float* b1 = (const float*)d_in[8];
    const float* m1 = (const float*)d_in[9];
    const float* v1 = (const float*)d_in[10];
    const float* W2 = (const float*)d_in[11];
    const float* g2 = (const float*)d_in[12];
    const float* b2 = (const float*)d_in[13];
    const float* m2 = (const float*)d_in[14];
    const float* v2 = (const float*)d_in[15];
    const float* Wf = (const float*)d_in[16];
    const float* gf = (const float*)d_in[17];
    const float* bf = (const float*)d_in[18];
    const float* mf = (const float*)d_in[19];
    const float* vf = (const float*)d_in[20];
    const float* We = (const float*)d_in[21];

    float* ws = (float*)d_ws;
    // workspace layout (floats); total ~20.9M floats = ~80 MiB
    float* hx     = ws;                         // 8*3*1024        = 24576
    float* cat    = hx + 24576;                 // 8*448*1024      = 3670016
    float* xx     = cat + 3670016;              // 8*1024          = 8192
    int*   idx    = (int*)(xx + 8192);          // 8*1024*20       = 163840
    float* D      = (float*)(idx + 163840);     // 8*1024*1024     = 8388608
    float* p      = D + 8388608;                // 8*512*1024      = 4194304
    float* dd     = p + 4194304;                // 8*512*1024      = 4194304
    float* wd     = dd + 4194304;               // 512*448         = 229376
    float* pooled = wd + 229376;                // 8*512           = 4096
    float* hf     = D;                          // reuse D region after top-k of final layer

    k_transpose<<<96, 256, 0, stream>>>(x, hx);

    auto run_layer = [&](const float* h, int C, int bstride, const float* W,
                         const float* g, const float* be, const float* m, const float* v,
                         int O, float* outp, int obstride) {
        k_xx<<<32, 256, 0, stream>>>(h, xx, C, bstride);
        k_dist<<<dim3(16, 16, 8), 256, 0, stream>>>(h, xx, D, C, bstride);
        k_topk<<<dim3(16, 8), 64, 0, stream>>>(D, idx);
        int wdn = O * C;
        k_wd<<<(wdn + 255) / 256, 256, 0, stream>>>(W, wd, C, O);
        k_gemm<<<dim3(16, O / 64, 8), 256, 0, stream>>>(W, 2 * C, h, bstride, C, p, O);
        k_gemm<<<dim3(16, O / 64, 8), 256, 0, stream>>>(wd, C, h, bstride, C, dd, O);
        k_edge<<<dim3(4, O, 8), 256, 0, stream>>>(p, dd, idx, g, be, m, v, outp, obstride, O);
    };

    // layer 0: in hx (C=3), out -> cat channels [0,64)
    run_layer(hx, 3, 3 * NV, W0, g0, b0, m0, v0, 64, cat, 448 * NV);
    // layer 1: in cat[0:64), out -> cat [64,192)
    run_layer(cat, 64, 448 * NV, W1, g1, b1, m1, v1, 128, cat + 64 * NV, 448 * NV);
    // layer 2: in cat[64:192), out -> cat [192,448)
    run_layer(cat + 64 * NV, 128, 448 * NV, W2, g2, b2, m2, v2, 256, cat + 192 * NV, 448 * NV);
    // final: in cat[0:448), out -> hf
    run_layer(cat, 448, 448 * NV, Wf, gf, bf, mf, vf, 512, hf, 512 * NV);

    k_pool<<<dim3(512, 8), 256, 0, stream>>>(hf, pooled);
    k_final<<<8, 256, 0, stream>>>(pooled, We, (float*)d_out);
}

// Round 2
// 1001.642 us; speedup vs baseline: 2.2416x; 2.2416x over previous
//
#include <hip/hip_runtime.h>
#include <cstdint>

#define KNN 20
#define BV 8
#define NV 1024

// ---------- transpose x [B,N,3] -> hx [B,3,N]
__global__ __launch_bounds__(256) void k_transpose(const float* __restrict__ x, float* __restrict__ hx) {
    int id = blockIdx.x * 256 + threadIdx.x;
    if (id >= BV * 3 * NV) return;
    int n = id % NV;
    int c = (id / NV) % 3;
    int b = id / (3 * NV);
    hx[id] = x[(b * NV + n) * 3 + c];
}

// ---------- xx[b][n] = sum_c h[b][c][n]^2
__global__ __launch_bounds__(256) void k_xx(const float* __restrict__ h, float* __restrict__ xx,
                                            int C, int bstride) {
    int id = blockIdx.x * 256 + threadIdx.x;
    int n = id % NV, b = id / NV;
    if (b >= BV) return;
    const float* hp = h + (size_t)b * bstride + n;
    float s = 0.f;
    for (int c = 0; c < C; ++c) { float v = hp[(size_t)c * NV]; s += v * v; }
    xx[b * NV + n] = s;
}

// ---------- D[b][i][j] = 2*sum_c h[c,i]h[c,j] - xx[i] - xx[j]   (neg sq dist)
// 128x128 tile, 256 threads, 8x8 micro-tile
__global__ __launch_bounds__(256) void k_dist(const float* __restrict__ h, const float* __restrict__ xx,
                                              float* __restrict__ D, int C, int bstride) {
    __shared__ float As[8][128], Bs[8][128];
    const int b = blockIdx.z, i0 = blockIdx.y * 128, j0 = blockIdx.x * 128;
    const int t = threadIdx.x, tx = t & 15, ty = t >> 4;
    float acc[8][8] = {};
    const float* hb = h + (size_t)b * bstride;
    for (int c0 = 0; c0 < C; c0 += 8) {
#pragma unroll
        for (int q = 0; q < 4; ++q) {
            int e = t + q * 256;
            int cc = e >> 7, ii = e & 127;
            bool ok = (c0 + cc) < C;
            As[cc][ii] = ok ? hb[(size_t)(c0 + cc) * NV + i0 + ii] : 0.f;
            Bs[cc][ii] = ok ? hb[(size_t)(c0 + cc) * NV + j0 + ii] : 0.f;
        }
        __syncthreads();
#pragma unroll
        for (int c = 0; c < 8; ++c) {
            float ar[8], br[8];
#pragma unroll
            for (int a = 0; a < 8; ++a) ar[a] = As[c][ty * 8 + a];
#pragma unroll
            for (int q = 0; q < 8; ++q) br[q] = Bs[c][tx * 8 + q];
#pragma unroll
            for (int a = 0; a < 8; ++a)
#pragma unroll
                for (int q = 0; q < 8; ++q) acc[a][q] += ar[a] * br[q];
        }
        __syncthreads();
    }
    const float* xb = xx + b * NV;
#pragma unroll
    for (int a = 0; a < 8; ++a) {
        int i = i0 + ty * 8 + a;
        float xi = xb[i];
        float* Dp = D + (size_t)b * NV * NV + (size_t)i * NV + j0 + tx * 8;
#pragma unroll
        for (int q = 0; q < 8; ++q)
            Dp[q] = 2.f * acc[a][q] - xi - xb[j0 + tx * 8 + q];
    }
}

// ---------- top-20 per row: one 64-lane wave per row, 4 waves/block.
// Each lane holds 16 candidates in regs + 16-bit alive mask (static indexing only).
__global__ __launch_bounds__(256) void k_topk(const float* __restrict__ D, int* __restrict__ idx) {
    const int wid = threadIdx.x >> 6, lane = threadIdx.x & 63;
    const int row = blockIdx.x * 4 + wid;            // [0, B*N)
    const float* Dr = D + (size_t)row * NV;
    float v[16];
#pragma unroll
    for (int e = 0; e < 16; ++e) v[e] = Dr[e * 64 + lane];   // global idx = e*64+lane
    unsigned alive = 0xFFFFu;
    int* op = idx + (size_t)row * KNN;
#pragma unroll 1
    for (int s = 0; s < KNN; ++s) {
        // masked local max over 16 regs (static indices, tie -> lower e)
        float bv = -3.4e38f; int be = 0;
#pragma unroll
        for (int e = 0; e < 16; ++e) {
            float vv = (alive & (1u << e)) ? v[e] : -3.4e38f;
            if (vv > bv) { bv = vv; be = e; }
        }
        int bi = be * 64 + lane;
        // butterfly argmax across wave; tie -> lower global index
#pragma unroll
        for (int off = 1; off < 64; off <<= 1) {
            float ov = __shfl_xor(bv, off, 64);
            int   oi = __shfl_xor(bi, off, 64);
            if (ov > bv || (ov == bv && oi < bi)) { bv = ov; bi = oi; }
        }
        if (lane == 0) op[s] = bi;
        if ((bi & 63) == lane) alive &= ~(1u << (bi >> 6));   // winner lane retires it
    }
}

// ---------- Wd[o][c] = W[o][C+c] - W[o][c]
__global__ __launch_bounds__(256) void k_wd(const float* __restrict__ W, float* __restrict__ Wd, int C, int O) {
    int id = blockIdx.x * 256 + threadIdx.x;
    if (id >= O * C) return;
    int c = id % C, o = id / C;
    Wd[id] = W[(size_t)o * 2 * C + C + c] - W[(size_t)o * 2 * C + c];
}

// ---------- out[b][o][n] = sum_c A[o][c] * h[b][c][n]
// 64x128 tile, 256 threads, 4x8 micro-tile
__global__ __launch_bounds__(256) void k_gemm(const float* __restrict__ A, int astride,
                                              const float* __restrict__ h, int bstride, int C,
                                              float* __restrict__ out, int O) {
    __shared__ float Ws[8][64], Hs[8][128];
    const int b = blockIdx.z, o0 = blockIdx.y * 64, n0 = blockIdx.x * 128;
    const int t = threadIdx.x, tx = t & 15, ty = t >> 4;
    float acc[4][8] = {};
    const float* hb = h + (size_t)b * bstride;
    for (int c0 = 0; c0 < C; c0 += 8) {
#pragma unroll
        for (int q = 0; q < 2; ++q) {       // Ws: 512 elems
            int e = t + q * 256;
            int oo = e >> 3, cc = e & 7;
            Ws[cc][oo] = ((c0 + cc) < C) ? A[(size_t)(o0 + oo) * astride + c0 + cc] : 0.f;
        }
#pragma unroll
        for (int q = 0; q < 4; ++q) {       // Hs: 1024 elems (coalesced)
            int e = t + q * 256;
            int cc = e >> 7, nn = e & 127;
            Hs[cc][nn] = ((c0 + cc) < C) ? hb[(size_t)(c0 + cc) * NV + n0 + nn] : 0.f;
        }
        __syncthreads();
#pragma unroll
        for (int c = 0; c < 8; ++c) {
            float ar[4], br[8];
#pragma unroll
            for (int a = 0; a < 4; ++a) ar[a] = Ws[c][ty * 4 + a];
#pragma unroll
            for (int q = 0; q < 8; ++q) br[q] = Hs[c][tx * 8 + q];
#pragma unroll
            for (int a = 0; a < 4; ++a)
#pragma unroll
                for (int q = 0; q < 8; ++q) acc[a][q] += ar[a] * br[q];
        }
        __syncthreads();
    }
#pragma unroll
    for (int a = 0; a < 4; ++a) {
        int o = o0 + ty * 4 + a;
        float* outp = out + ((size_t)b * O + o) * NV + n0 + tx * 8;
#pragma unroll
        for (int q = 0; q < 8; ++q) outp[q] = acc[a][q];
    }
}

// ---------- h_out[b][o][n] = mean_k lrelu( a*(p[b][o][idx[n][k]] + d[b][o][n]) + c0 )
__global__ __launch_bounds__(256) void k_edge(const float* __restrict__ p, const float* __restrict__ dd,
                                              const int* __restrict__ idx,
                                              const float* __restrict__ ga, const float* __restrict__ be,
                                              const float* __restrict__ mu, const float* __restrict__ va,
                                              float* __restrict__ out, int out_bstride, int O) {
    const int n = blockIdx.x * 256 + threadIdx.x;
    const int o = blockIdx.y, b = blockIdx.z;
    const float a  = ga[o] / sqrtf(va[o] + 1e-5f);
    const float c0 = be[o] - mu[o] * a;
    const float* pb = p + ((size_t)b * O + o) * NV;
    const float dv  = dd[((size_t)b * O + o) * NV + n];
    const int* ip   = idx + ((size_t)b * NV + n) * KNN;
    float s = 0.f;
#pragma unroll
    for (int k = 0; k < KNN; ++k) {
        int j = ip[k];
        float y = fmaf(a, pb[j] + dv, c0);
        s += (y > 0.f) ? y : 0.2f * y;
    }
    out[(size_t)b * out_bstride + (size_t)o * NV + n] = s * (1.f / KNN);
}

// ---------- pooled[b][o] = mean_n hf[b][o][n]
__global__ __launch_bounds__(256) void k_pool(const float* __restrict__ hf, float* __restrict__ pooled) {
    const int o = blockIdx.x, b = blockIdx.y;
    const float* hp = hf + ((size_t)b * 512 + o) * NV;
    float s = 0.f;
    for (int i = threadIdx.x; i < NV; i += 256) s += hp[i];
#pragma unroll
    for (int off = 32; off > 0; off >>= 1) s += __shfl_down(s, off, 64);
    __shared__ float red[4];
    if ((threadIdx.x & 63) == 0) red[threadIdx.x >> 6] = s;
    __syncthreads();
    if (threadIdx.x == 0)
        pooled[(size_t)b * 512 + o] = (red[0] + red[1] + red[2] + red[3]) * (1.f / NV);
}

// ---------- out[b][j] = sum_o pooled[b][o] * We[j][o]
__global__ __launch_bounds__(256) void k_final(const float* __restrict__ pooled, const float* __restrict__ We,
                                               float* __restrict__ out) {
    const int j = threadIdx.x, b = blockIdx.x;
    __shared__ float ps[512];
    for (int o = threadIdx.x; o < 512; o += 256) ps[o] = pooled[b * 512 + o];
    __syncthreads();
    float s = 0.f;
    for (int o = 0; o < 512; ++o) s += ps[o] * We[(size_t)j * 512 + o];
    out[b * 256 + j] = s;
}

extern "C" void kernel_launch(void* const* d_in, const int* in_sizes, int n_in,
                              void* d_out, int out_size, void* d_ws, size_t ws_size,
                              hipStream_t stream) {
    const float* x  = (const float*)d_in[0];
    const float* W0 = (const float*)d_in[1];
    const float* g0 = (const float*)d_in[2];
    const float* b0 = (const float*)d_in[3];
    const float* m0 = (const float*)d_in[4];
    const float* v0 = (const float*)d_in[5];
    const float* W1 = (const float*)d_in[6];
    const float* g1 = (const float*)d_in[7];
    const float* b1 = (const float*)d_in[8];
    const float* m1 = (const float*)d_in[9];
    const float* v1 = (const float*)d_in[10];
    const float* W2 = (const float*)d_in[11];
    const float* g2 = (const float*)d_in[12];
    const float* b2 = (const float*)d_in[13];
    const float* m2 = (const float*)d_in[14];
    const float* v2 = (const float*)d_in[15];
    const float* Wf = (const float*)d_in[16];
    const float* gf = (const float*)d_in[17];
    const float* bf = (const float*)d_in[18];
    const float* mf = (const float*)d_in[19];
    const float* vf = (const float*)d_in[20];
    const float* We = (const float*)d_in[21];

    float* ws = (float*)d_ws;
    float* hx     = ws;                         // 8*3*1024        = 24576
    float* cat    = hx + 24576;                 // 8*448*1024      = 3670016
    float* xx     = cat + 3670016;              // 8*1024          = 8192
    int*   idx    = (int*)(xx + 8192);          // 8*1024*20       = 163840
    float* D      = (float*)(idx + 163840);     // 8*1024*1024     = 8388608
    float* p      = D + 8388608;                // 8*512*1024      = 4194304
    float* dd     = p + 4194304;                // 8*512*1024      = 4194304
    float* wd     = dd + 4194304;               // 512*448         = 229376
    float* pooled = wd + 229376;                // 8*512           = 4096
    float* hf     = D;                          // reuse D region after final top-k

    k_transpose<<<96, 256, 0, stream>>>(x, hx);

    auto run_layer = [&](const float* h, int C, int bstride, const float* W,
                         const float* g, const float* be, const float* m, const float* v,
                         int O, float* outp, int obstride) {
        k_xx<<<32, 256, 0, stream>>>(h, xx, C, bstride);
        k_dist<<<dim3(8, 8, 8), 256, 0, stream>>>(h, xx, D, C, bstride);
        k_topk<<<2048, 256, 0, stream>>>(D, idx);
        int wdn = O * C;
        k_wd<<<(wdn + 255) / 256, 256, 0, stream>>>(W, wd, C, O);
        k_gemm<<<dim3(8, O / 64, 8), 256, 0, stream>>>(W, 2 * C, h, bstride, C, p, O);
        k_gemm<<<dim3(8, O / 64, 8), 256, 0, stream>>>(wd, C, h, bstride, C, dd, O);
        k_edge<<<dim3(4, O, 8), 256, 0, stream>>>(p, dd, idx, g, be, m, v, outp, obstride, O);
    };

    run_layer(hx, 3, 3 * NV, W0, g0, b0, m0, v0, 64, cat, 448 * NV);
    run_layer(cat, 64, 448 * NV, W1, g1, b1, m1, v1, 128, cat + 64 * NV, 448 * NV);
    run_layer(cat + 64 * NV, 128, 448 * NV, W2, g2, b2, m2, v2, 256, cat + 192 * NV, 448 * NV);
    run_layer(cat, 448, 448 * NV, Wf, gf, bf, mf, vf, 512, hf, 512 * NV);

    k_pool<<<dim3(512, 8), 256, 0, stream>>>(hf, pooled);
    k_final<<<8, 256, 0, stream>>>(pooled, We, (float*)d_out);
}

// Round 3
// 967.807 us; speedup vs baseline: 2.3200x; 1.0350x over previous
//
#include <hip/hip_runtime.h>
#include <cstdint>

#define KNN 20
#define BV 8
#define NV 1024

// ---------- transpose x [B,N,3] -> hx [B,3,N]
__global__ __launch_bounds__(256) void k_transpose(const float* __restrict__ x, float* __restrict__ hx) {
    int id = blockIdx.x * 256 + threadIdx.x;
    if (id >= BV * 3 * NV) return;
    int n = id % NV;
    int c = (id / NV) % 3;
    int b = id / (3 * NV);
    hx[id] = x[(b * NV + n) * 3 + c];
}

// ---------- xx[b][n] = sum_c h[b][c][n]^2
__global__ __launch_bounds__(256) void k_xx(const float* __restrict__ h, float* __restrict__ xx,
                                            int C, int bstride) {
    int id = blockIdx.x * 256 + threadIdx.x;
    int n = id % NV, b = id / NV;
    if (b >= BV) return;
    const float* hp = h + (size_t)b * bstride + n;
    float s = 0.f;
    for (int c = 0; c < C; ++c) { float v = hp[(size_t)c * NV]; s += v * v; }
    xx[b * NV + n] = s;
}

// ---------- FUSED kNN: compute neg-sqdist rows in registers, top-20 in-wave, no D matrix.
// grid (B, N/32); block 512 = 8 waves; wave w owns rows i0+4w..+3; lane owns 16 j's.
__global__ __launch_bounds__(512) void k_knn(const float* __restrict__ h, const float* __restrict__ xx,
                                             int C, int bstride, int* __restrict__ idx) {
    __shared__ float Bs[8][1024];
    const int b = blockIdx.x, i0 = blockIdx.y * 32;
    const int t = threadIdx.x, lane = t & 63, w = t >> 6;
    const int irow = i0 + w * 4;
    float acc[4][16] = {};
    const float* hb = h + (size_t)b * bstride;

    for (int c0 = 0; c0 < C; c0 += 8) {
        __syncthreads();
#pragma unroll
        for (int r = 0; r < 4; ++r) {              // stage Bs[8][1024] = h[c0..c0+7][:]
            int e = r * 512 + t;                   // 0..2047 float4 groups
            int cc = e >> 8, jj = e & 255;
            float4 v = make_float4(0.f, 0.f, 0.f, 0.f);
            if (c0 + cc < C) v = *(const float4*)&hb[(size_t)(c0 + cc) * NV + jj * 4];
            *(float4*)&Bs[cc][jj * 4] = v;
        }
        __syncthreads();
#pragma unroll
        for (int c = 0; c < 8; ++c) {
            float4 arv = *(const float4*)&Bs[c][irow];     // wave-uniform broadcast
            float ar[4] = {arv.x, arv.y, arv.z, arv.w};
            float br[16];
#pragma unroll
            for (int g = 0; g < 4; ++g) {
                float4 bv = *(const float4*)&Bs[c][g * 256 + (lane << 2)];  // conflict-free b128
                br[g * 4 + 0] = bv.x; br[g * 4 + 1] = bv.y;
                br[g * 4 + 2] = bv.z; br[g * 4 + 3] = bv.w;
            }
#pragma unroll
            for (int a = 0; a < 4; ++a)
#pragma unroll
                for (int q = 0; q < 16; ++q) acc[a][q] += ar[a] * br[q];
        }
    }

    // neg sqdist = 2*dot - xx_i - xx_j
    const float* xb = xx + b * NV;
    float xxj[16];
#pragma unroll
    for (int g = 0; g < 4; ++g) {
        float4 xv = *(const float4*)&xb[g * 256 + (lane << 2)];
        xxj[g * 4 + 0] = xv.x; xxj[g * 4 + 1] = xv.y;
        xxj[g * 4 + 2] = xv.z; xxj[g * 4 + 3] = xv.w;
    }
#pragma unroll
    for (int a = 0; a < 4; ++a) {
        float xi = xb[irow + a];
#pragma unroll
        for (int q = 0; q < 16; ++q) acc[a][q] = 2.f * acc[a][q] - xi - xxj[q];
    }

    // wave-parallel top-20 per row, scores already in registers
#pragma unroll
    for (int a = 0; a < 4; ++a) {
        unsigned alive = 0xFFFFu;
        int* op = idx + ((size_t)(b * NV + irow + a)) * KNN;
#pragma unroll 1
        for (int s = 0; s < KNN; ++s) {
            float bv = -3.4e38f; int bq = 0;
#pragma unroll
            for (int q = 0; q < 16; ++q) {          // static idx only; tie -> lower q (= lower j)
                float vv = (alive & (1u << q)) ? acc[a][q] : -3.4e38f;
                if (vv > bv) { bv = vv; bq = q; }
            }
            int bj = ((bq >> 2) << 8) + (lane << 2) + (bq & 3);
#pragma unroll
            for (int off = 1; off < 64; off <<= 1) { // butterfly argmax; tie -> lower j
                float ov = __shfl_xor(bv, off, 64);
                int   oj = __shfl_xor(bj, off, 64);
                if (ov > bv || (ov == bv && oj < bj)) { bv = ov; bj = oj; }
            }
            if (lane == 0) op[s] = bj;
            if (((bj >> 2) & 63) == lane)            // winner lane retires its candidate
                alive &= ~(1u << (((bj >> 8) << 2) | (bj & 3)));
        }
    }
}

// ---------- pack A = [ Wl ; Wr - Wl ]  (2O x C)
__global__ __launch_bounds__(256) void k_pack(const float* __restrict__ W, float* __restrict__ wb,
                                              int C, int O) {
    int id = blockIdx.x * 256 + threadIdx.x;
    if (id >= 2 * O * C) return;
    int c = id % C, o = (id / C) % O, half = id / (C * O);
    float wl = W[(size_t)o * 2 * C + c];
    wb[id] = half ? (W[(size_t)o * 2 * C + C + c] - wl) : wl;
}

// ---------- out[b][o][n] = sum_c A[o][c] * h[b][c][n]   (64x128 tile, 4x8 micro)
__global__ __launch_bounds__(256) void k_gemm(const float* __restrict__ A, int astride,
                                              const float* __restrict__ h, int bstride, int C,
                                              float* __restrict__ out, int O) {
    __shared__ float Ws[8][64], Hs[8][128];
    const int b = blockIdx.z, o0 = blockIdx.y * 64, n0 = blockIdx.x * 128;
    const int t = threadIdx.x, tx = t & 15, ty = t >> 4;
    float acc[4][8] = {};
    const float* hb = h + (size_t)b * bstride;
    for (int c0 = 0; c0 < C; c0 += 8) {
#pragma unroll
        for (int q = 0; q < 2; ++q) {
            int e = t + q * 256;
            int oo = e >> 3, cc = e & 7;
            Ws[cc][oo] = ((c0 + cc) < C) ? A[(size_t)(o0 + oo) * astride + c0 + cc] : 0.f;
        }
        {
            int cc = t >> 5, nn4 = t & 31;
            float4 v = make_float4(0.f, 0.f, 0.f, 0.f);
            if (c0 + cc < C) v = *(const float4*)&hb[(size_t)(c0 + cc) * NV + n0 + nn4 * 4];
            *(float4*)&Hs[cc][nn4 * 4] = v;
        }
        __syncthreads();
#pragma unroll
        for (int c = 0; c < 8; ++c) {
            float4 wv = *(const float4*)&Ws[c][ty * 4];
            float ar[4] = {wv.x, wv.y, wv.z, wv.w};
            float br[8];
            float4 h0 = *(const float4*)&Hs[c][tx * 4];          // conflict-free
            float4 h1 = *(const float4*)&Hs[c][64 + tx * 4];
            br[0] = h0.x; br[1] = h0.y; br[2] = h0.z; br[3] = h0.w;
            br[4] = h1.x; br[5] = h1.y; br[6] = h1.z; br[7] = h1.w;
#pragma unroll
            for (int a = 0; a < 4; ++a)
#pragma unroll
                for (int q = 0; q < 8; ++q) acc[a][q] += ar[a] * br[q];
        }
        __syncthreads();
    }
#pragma unroll
    for (int a = 0; a < 4; ++a) {
        int o = o0 + ty * 4 + a;
        float* outp = out + ((size_t)b * O + o) * NV + n0;
        float4 s0 = make_float4(acc[a][0], acc[a][1], acc[a][2], acc[a][3]);
        float4 s1 = make_float4(acc[a][4], acc[a][5], acc[a][6], acc[a][7]);
        *(float4*)&outp[tx * 4] = s0;
        *(float4*)&outp[64 + tx * 4] = s1;
    }
}

// ---------- h_out[b][o][n] = mean_k lrelu( a*(p[b][o][idx[n][k]] + d[b][o][n]) + c0 )
// pd holds [b][2O][N]: rows [0,O) = p (neighbor term), rows [O,2O) = d (center term)
__global__ __launch_bounds__(256) void k_edge(const float* __restrict__ pd,
                                              const int* __restrict__ idx,
                                              const float* __restrict__ ga, const float* __restrict__ be,
                                              const float* __restrict__ mu, const float* __restrict__ va,
                                              float* __restrict__ out, int out_bstride, int O) {
    const int n = blockIdx.x * 256 + threadIdx.x;
    const int o = blockIdx.y, b = blockIdx.z;
    const float a  = ga[o] / sqrtf(va[o] + 1e-5f);
    const float c0 = be[o] - mu[o] * a;
    const float* pb = pd + ((size_t)b * 2 * O + o) * NV;
    const float dv  = pd[((size_t)b * 2 * O + O + o) * NV + n];
    const int* ip   = idx + ((size_t)b * NV + n) * KNN;
    float s = 0.f;
#pragma unroll
    for (int k = 0; k < KNN; ++k) {
        int j = ip[k];
        float y = fmaf(a, pb[j] + dv, c0);
        s += (y > 0.f) ? y : 0.2f * y;
    }
    out[(size_t)b * out_bstride + (size_t)o * NV + n] = s * (1.f / KNN);
}

// ---------- pooled[b][o] = mean_n hf[b][o][n]
__global__ __launch_bounds__(256) void k_pool(const float* __restrict__ hf, float* __restrict__ pooled) {
    const int o = blockIdx.x, b = blockIdx.y;
    const float* hp = hf + ((size_t)b * 512 + o) * NV;
    float s = 0.f;
    for (int i = threadIdx.x; i < NV; i += 256) s += hp[i];
#pragma unroll
    for (int off = 32; off > 0; off >>= 1) s += __shfl_down(s, off, 64);
    __shared__ float red[4];
    if ((threadIdx.x & 63) == 0) red[threadIdx.x >> 6] = s;
    __syncthreads();
    if (threadIdx.x == 0)
        pooled[(size_t)b * 512 + o] = (red[0] + red[1] + red[2] + red[3]) * (1.f / NV);
}

// ---------- out[b][j] = sum_o pooled[b][o] * We[j][o]
__global__ __launch_bounds__(256) void k_final(const float* __restrict__ pooled, const float* __restrict__ We,
                                               float* __restrict__ out) {
    const int j = threadIdx.x, b = blockIdx.x;
    __shared__ float ps[512];
    for (int o = threadIdx.x; o < 512; o += 256) ps[o] = pooled[b * 512 + o];
    __syncthreads();
    float s = 0.f;
    for (int o = 0; o < 512; ++o) s += ps[o] * We[(size_t)j * 512 + o];
    out[b * 256 + j] = s;
}

extern "C" void kernel_launch(void* const* d_in, const int* in_sizes, int n_in,
                              void* d_out, int out_size, void* d_ws, size_t ws_size,
                              hipStream_t stream) {
    const float* x  = (const float*)d_in[0];
    const float* W0 = (const float*)d_in[1];
    const float* g0 = (const float*)d_in[2];
    const float* b0 = (const float*)d_in[3];
    const float* m0 = (const float*)d_in[4];
    const float* v0 = (const float*)d_in[5];
    const float* W1 = (const float*)d_in[6];
    const float* g1 = (const float*)d_in[7];
    const float* b1 = (const float*)d_in[8];
    const float* m1 = (const float*)d_in[9];
    const float* v1 = (const float*)d_in[10];
    const float* W2 = (const float*)d_in[11];
    const float* g2 = (const float*)d_in[12];
    const float* b2 = (const float*)d_in[13];
    const float* m2 = (const float*)d_in[14];
    const float* v2 = (const float*)d_in[15];
    const float* Wf = (const float*)d_in[16];
    const float* gf = (const float*)d_in[17];
    const float* bf = (const float*)d_in[18];
    const float* mf = (const float*)d_in[19];
    const float* vf = (const float*)d_in[20];
    const float* We = (const float*)d_in[21];

    float* ws = (float*)d_ws;
    float* hx     = ws;                         // 24576
    float* cat    = hx + 24576;                 // 3670016
    float* xx     = cat + 3670016;              // 8192
    int*   idx    = (int*)(xx + 8192);          // 163840 ints
    float* pd     = (float*)(idx + 163840);     // 8*1024*1024 = 8388608 (2O max = 1024)
    float* wb     = pd + 8388608;               // 2*512*448 = 458752
    float* hf     = wb + 458752;                // 8*512*1024 = 4194304
    float* pooled = hf + 4194304;               // 4096

    k_transpose<<<96, 256, 0, stream>>>(x, hx);

    auto run_layer = [&](const float* h, int C, int bstride, const float* W,
                         const float* g, const float* be, const float* m, const float* v,
                         int O, float* outp, int obstride) {
        k_xx<<<32, 256, 0, stream>>>(h, xx, C, bstride);
        k_knn<<<dim3(8, 32), 512, 0, stream>>>(h, xx, C, bstride, idx);
        int pn = 2 * O * C;
        k_pack<<<(pn + 255) / 256, 256, 0, stream>>>(W, wb, C, O);
        k_gemm<<<dim3(8, 2 * O / 64, 8), 256, 0, stream>>>(wb, C, h, bstride, C, pd, 2 * O);
        k_edge<<<dim3(4, O, 8), 256, 0, stream>>>(pd, idx, g, be, m, v, outp, obstride, O);
    };

    run_layer(hx, 3, 3 * NV, W0, g0, b0, m0, v0, 64, cat, 448 * NV);
    run_layer(cat, 64, 448 * NV, W1, g1, b1, m1, v1, 128, cat + 64 * NV, 448 * NV);
    run_layer(cat + 64 * NV, 128, 448 * NV, W2, g2, b2, m2, v2, 256, cat + 192 * NV, 448 * NV);
    run_layer(cat, 448, 448 * NV, Wf, gf, bf, mf, vf, 512, hf, 512 * NV);

    k_pool<<<dim3(512, 8), 256, 0, stream>>>(hf, pooled);
    k_final<<<8, 256, 0, stream>>>(pooled, We, (float*)d_out);
}

// Round 4
// 843.454 us; speedup vs baseline: 2.6620x; 1.1474x over previous
//
#include <hip/hip_runtime.h>
#include <cstdint>

#define KNN 20
#define BV 8
#define NV 1024

// ---------- transpose x [B,N,3] -> hx [B,3,N]
__global__ __launch_bounds__(256) void k_transpose(const float* __restrict__ x, float* __restrict__ hx) {
    int id = blockIdx.x * 256 + threadIdx.x;
    if (id >= BV * 3 * NV) return;
    int n = id % NV;
    int c = (id / NV) % 3;
    int b = id / (3 * NV);
    hx[id] = x[(b * NV + n) * 3 + c];
}

// ---------- xx[b][n] = sum_c h[b][c][n]^2
__global__ __launch_bounds__(256) void k_xx(const float* __restrict__ h, float* __restrict__ xx,
                                            int C, int bstride) {
    int id = blockIdx.x * 256 + threadIdx.x;
    int n = id % NV, b = id / NV;
    if (b >= BV) return;
    const float* hp = h + (size_t)b * bstride + n;
    float s = 0.f;
    for (int c = 0; c < C; ++c) { float v = hp[(size_t)c * NV]; s += v * v; }
    xx[b * NV + n] = s;
}

// ---------- FUSED kNN: neg-sqdist rows in registers, top-20 in-wave, no D matrix.
// grid (B, N/32); block 512 = 8 waves; wave w owns rows i0+4w..+3; lane owns 16 j's.
__global__ __launch_bounds__(512) void k_knn(const float* __restrict__ h, const float* __restrict__ xx,
                                             int C, int bstride, int* __restrict__ idx) {
    __shared__ float Bs[8][1024];
    const int b = blockIdx.x, i0 = blockIdx.y * 32;
    const int t = threadIdx.x, lane = t & 63, w = t >> 6;
    const int irow = i0 + w * 4;
    float acc[4][16] = {};
    const float* hb = h + (size_t)b * bstride;

    for (int c0 = 0; c0 < C; c0 += 8) {
        __syncthreads();
#pragma unroll
        for (int r = 0; r < 4; ++r) {              // stage Bs[8][1024] = h[c0..c0+7][:]
            int e = r * 512 + t;                   // 2048 float4 groups
            int cc = e >> 8, jj = e & 255;
            float4 v = make_float4(0.f, 0.f, 0.f, 0.f);
            if (c0 + cc < C) v = *(const float4*)&hb[(size_t)(c0 + cc) * NV + jj * 4];
            *(float4*)&Bs[cc][jj * 4] = v;
        }
        __syncthreads();
#pragma unroll
        for (int c = 0; c < 8; ++c) {
            float4 arv = *(const float4*)&Bs[c][irow];     // wave-uniform broadcast
            float ar[4] = {arv.x, arv.y, arv.z, arv.w};
            float br[16];
#pragma unroll
            for (int g = 0; g < 4; ++g) {
                float4 bv = *(const float4*)&Bs[c][g * 256 + (lane << 2)];  // conflict-free b128
                br[g * 4 + 0] = bv.x; br[g * 4 + 1] = bv.y;
                br[g * 4 + 2] = bv.z; br[g * 4 + 3] = bv.w;
            }
#pragma unroll
            for (int a = 0; a < 4; ++a)
#pragma unroll
                for (int q = 0; q < 16; ++q) acc[a][q] += ar[a] * br[q];
        }
    }

    // neg sqdist = 2*dot - xx_i - xx_j
    const float* xb = xx + b * NV;
    float xxj[16];
#pragma unroll
    for (int g = 0; g < 4; ++g) {
        float4 xv = *(const float4*)&xb[g * 256 + (lane << 2)];
        xxj[g * 4 + 0] = xv.x; xxj[g * 4 + 1] = xv.y;
        xxj[g * 4 + 2] = xv.z; xxj[g * 4 + 3] = xv.w;
    }
#pragma unroll
    for (int a = 0; a < 4; ++a) {
        float xi = xb[irow + a];
#pragma unroll
        for (int q = 0; q < 16; ++q) acc[a][q] = 2.f * acc[a][q] - xi - xxj[q];
    }

    // ---- wave-parallel top-20, 4 rows' chains INTERLEAVED for ILP
    int* opb = idx + ((size_t)(b * NV + irow)) * KNN;   // rows contiguous: [a*KNN + s]
#pragma unroll 1
    for (int s = 0; s < KNN; ++s) {
        unsigned gsu[4], mysu[4]; int myj[4];
#pragma unroll
        for (int a = 0; a < 4; ++a) {
            float bv = acc[a][0]; int bq = 0;
#pragma unroll
            for (int q = 1; q < 16; ++q)            // static idx; strict > keeps lower q (= lower j)
                if (acc[a][q] > bv) { bv = acc[a][q]; bq = q; }
            unsigned u = __float_as_uint(bv);
            unsigned su = ((int)u < 0) ? ~u : (u | 0x80000000u);   // sortable uint
            mysu[a] = su; gsu[a] = su;
            myj[a] = ((bq >> 2) << 8) | (lane << 2) | (bq & 3);
        }
#pragma unroll
        for (int off = 1; off < 64; off <<= 1) {    // 4 interleaved value-butterflies
#pragma unroll
            for (int a = 0; a < 4; ++a) {
                unsigned o = __shfl_xor(gsu[a], off, 64);
                gsu[a] = (o > gsu[a]) ? o : gsu[a];
            }
        }
#pragma unroll
        for (int a = 0; a < 4; ++a) {
            unsigned long long m = __ballot(mysu[a] == gsu[a]);
            int j;
            if (m & (m - 1)) {                      // rare value tie across lanes: lowest j wins
                int nj = (mysu[a] == gsu[a]) ? (1023 - myj[a]) : -1;
#pragma unroll
                for (int off = 1; off < 64; off <<= 1) {
                    int o = __shfl_xor(nj, off, 64);
                    nj = (o > nj) ? o : nj;
                }
                j = 1023 - nj;
            } else {                                // unique winner: broadcast its j
                int wl = (int)__ffsll(m) - 1;
                j = __builtin_amdgcn_readlane(myj[a], wl);
            }
            if (lane == 0) opb[a * KNN + s] = j;
            // winner lane poisons its extracted slot (static-index cndmask chain)
            int wq = (((j >> 2) & 63) == lane) ? (((j >> 8) << 2) | (j & 3)) : 99;
#pragma unroll
            for (int q = 0; q < 16; ++q)
                if (wq == q) acc[a][q] = -3.4e38f;
        }
    }
}

// ---------- pack A = [ Wl ; Wr - Wl ]  (2O x C)
__global__ __launch_bounds__(256) void k_pack(const float* __restrict__ W, float* __restrict__ wb,
                                              int C, int O) {
    int id = blockIdx.x * 256 + threadIdx.x;
    if (id >= 2 * O * C) return;
    int c = id % C, o = (id / C) % O, half = id / (C * O);
    float wl = W[(size_t)o * 2 * C + c];
    wb[id] = half ? (W[(size_t)o * 2 * C + C + c] - wl) : wl;
}

// ---------- out[b][o][n] = sum_c A[o][c] * h[b][c][n]   (64x128 tile, 4x8 micro)
__global__ __launch_bounds__(256) void k_gemm(const float* __restrict__ A, int astride,
                                              const float* __restrict__ h, int bstride, int C,
                                              float* __restrict__ out, int O) {
    __shared__ float Ws[8][64], Hs[8][128];
    const int b = blockIdx.z, o0 = blockIdx.y * 64, n0 = blockIdx.x * 128;
    const int t = threadIdx.x, tx = t & 15, ty = t >> 4;
    float acc[4][8] = {};
    const float* hb = h + (size_t)b * bstride;
    for (int c0 = 0; c0 < C; c0 += 8) {
#pragma unroll
        for (int q = 0; q < 2; ++q) {
            int e = t + q * 256;
            int oo = e >> 3, cc = e & 7;
            Ws[cc][oo] = ((c0 + cc) < C) ? A[(size_t)(o0 + oo) * astride + c0 + cc] : 0.f;
        }
        {
            int cc = t >> 5, nn4 = t & 31;
            float4 v = make_float4(0.f, 0.f, 0.f, 0.f);
            if (c0 + cc < C) v = *(const float4*)&hb[(size_t)(c0 + cc) * NV + n0 + nn4 * 4];
            *(float4*)&Hs[cc][nn4 * 4] = v;
        }
        __syncthreads();
#pragma unroll
        for (int c = 0; c < 8; ++c) {
            float4 wv = *(const float4*)&Ws[c][ty * 4];
            float ar[4] = {wv.x, wv.y, wv.z, wv.w};
            float br[8];
            float4 h0 = *(const float4*)&Hs[c][tx * 4];
            float4 h1 = *(const float4*)&Hs[c][64 + tx * 4];
            br[0] = h0.x; br[1] = h0.y; br[2] = h0.z; br[3] = h0.w;
            br[4] = h1.x; br[5] = h1.y; br[6] = h1.z; br[7] = h1.w;
#pragma unroll
            for (int a = 0; a < 4; ++a)
#pragma unroll
                for (int q = 0; q < 8; ++q) acc[a][q] += ar[a] * br[q];
        }
        __syncthreads();
    }
#pragma unroll
    for (int a = 0; a < 4; ++a) {
        int o = o0 + ty * 4 + a;
        float* outp = out + ((size_t)b * O + o) * NV + n0;
        float4 s0 = make_float4(acc[a][0], acc[a][1], acc[a][2], acc[a][3]);
        float4 s1 = make_float4(acc[a][4], acc[a][5], acc[a][6], acc[a][7]);
        *(float4*)&outp[tx * 4] = s0;
        *(float4*)&outp[64 + tx * 4] = s1;
    }
}

// ---------- h_out[b][o][n] = mean_k lrelu( a*(p[b][o][idx[n][k]] + d[b][o][n]) + c0 )
__global__ __launch_bounds__(256) void k_edge(const float* __restrict__ pd,
                                              const int* __restrict__ idx,
                                              const float* __restrict__ ga, const float* __restrict__ be,
                                              const float* __restrict__ mu, const float* __restrict__ va,
                                              float* __restrict__ out, int out_bstride, int O) {
    const int n = blockIdx.x * 256 + threadIdx.x;
    const int o = blockIdx.y, b = blockIdx.z;
    const float a  = ga[o] / sqrtf(va[o] + 1e-5f);
    const float c0 = be[o] - mu[o] * a;
    const float* pb = pd + ((size_t)b * 2 * O + o) * NV;
    const float dv  = pd[((size_t)b * 2 * O + O + o) * NV + n];
    const int* ip   = idx + ((size_t)b * NV + n) * KNN;
    float s = 0.f;
#pragma unroll
    for (int k = 0; k < KNN; ++k) {
        int j = ip[k];
        float y = fmaf(a, pb[j] + dv, c0);
        s += (y > 0.f) ? y : 0.2f * y;
    }
    out[(size_t)b * out_bstride + (size_t)o * NV + n] = s * (1.f / KNN);
}

// ---------- pooled[b][o] = mean_n hf[b][o][n]
__global__ __launch_bounds__(256) void k_pool(const float* __restrict__ hf, float* __restrict__ pooled) {
    const int o = blockIdx.x, b = blockIdx.y;
    const float* hp = hf + ((size_t)b * 512 + o) * NV;
    float s = 0.f;
    for (int i = threadIdx.x; i < NV; i += 256) s += hp[i];
#pragma unroll
    for (int off = 32; off > 0; off >>= 1) s += __shfl_down(s, off, 64);
    __shared__ float red[4];
    if ((threadIdx.x & 63) == 0) red[threadIdx.x >> 6] = s;
    __syncthreads();
    if (threadIdx.x == 0)
        pooled[(size_t)b * 512 + o] = (red[0] + red[1] + red[2] + red[3]) * (1.f / NV);
}

// ---------- out[b][j] = sum_o pooled[b][o] * We[j][o]
__global__ __launch_bounds__(256) void k_final(const float* __restrict__ pooled, const float* __restrict__ We,
                                               float* __restrict__ out) {
    const int j = threadIdx.x, b = blockIdx.x;
    __shared__ float ps[512];
    for (int o = threadIdx.x; o < 512; o += 256) ps[o] = pooled[b * 512 + o];
    __syncthreads();
    float s = 0.f;
    for (int o = 0; o < 512; ++o) s += ps[o] * We[(size_t)j * 512 + o];
    out[b * 256 + j] = s;
}

extern "C" void kernel_launch(void* const* d_in, const int* in_sizes, int n_in,
                              void* d_out, int out_size, void* d_ws, size_t ws_size,
                              hipStream_t stream) {
    const float* x  = (const float*)d_in[0];
    const float* W0 = (const float*)d_in[1];
    const float* g0 = (const float*)d_in[2];
    const float* b0 = (const float*)d_in[3];
    const float* m0 = (const float*)d_in[4];
    const float* v0 = (const float*)d_in[5];
    const float* W1 = (const float*)d_in[6];
    const float* g1 = (const float*)d_in[7];
    const float* b1 = (const float*)d_in[8];
    const float* m1 = (const float*)d_in[9];
    const float* v1 = (const float*)d_in[10];
    const float* W2 = (const float*)d_in[11];
    const float* g2 = (const float*)d_in[12];
    const float* b2 = (const float*)d_in[13];
    const float* m2 = (const float*)d_in[14];
    const float* v2 = (const float*)d_in[15];
    const float* Wf = (const float*)d_in[16];
    const float* gf = (const float*)d_in[17];
    const float* bf = (const float*)d_in[18];
    const float* mf = (const float*)d_in[19];
    const float* vf = (const float*)d_in[20];
    const float* We = (const float*)d_in[21];

    float* ws = (float*)d_ws;
    float* hx     = ws;                         // 24576
    float* cat    = hx + 24576;                 // 3670016
    float* xx     = cat + 3670016;              // 8192
    int*   idx    = (int*)(xx + 8192);          // 163840 ints
    float* pd     = (float*)(idx + 163840);     // 8388608 (2O max = 1024)
    float* wb     = pd + 8388608;               // 458752
    float* hf     = wb + 458752;                // 4194304
    float* pooled = hf + 4194304;               // 4096

    k_transpose<<<96, 256, 0, stream>>>(x, hx);

    auto run_layer = [&](const float* h, int C, int bstride, const float* W,
                         const float* g, const float* be, const float* m, const float* v,
                         int O, float* outp, int obstride) {
        k_xx<<<32, 256, 0, stream>>>(h, xx, C, bstride);
        k_knn<<<dim3(8, 32), 512, 0, stream>>>(h, xx, C, bstride, idx);
        int pn = 2 * O * C;
        k_pack<<<(pn + 255) / 256, 256, 0, stream>>>(W, wb, C, O);
        k_gemm<<<dim3(8, 2 * O / 64, 8), 256, 0, stream>>>(wb, C, h, bstride, C, pd, 2 * O);
        k_edge<<<dim3(4, O, 8), 256, 0, stream>>>(pd, idx, g, be, m, v, outp, obstride, O);
    };

    run_layer(hx, 3, 3 * NV, W0, g0, b0, m0, v0, 64, cat, 448 * NV);
    run_layer(cat, 64, 448 * NV, W1, g1, b1, m1, v1, 128, cat + 64 * NV, 448 * NV);
    run_layer(cat + 64 * NV, 128, 448 * NV, W2, g2, b2, m2, v2, 256, cat + 192 * NV, 448 * NV);
    run_layer(cat, 448, 448 * NV, Wf, gf, bf, mf, vf, 512, hf, 512 * NV);

    k_pool<<<dim3(512, 8), 256, 0, stream>>>(hf, pooled);
    k_final<<<8, 256, 0, stream>>>(pooled, We, (float*)d_out);
}